// Round 1
// baseline (574.941 us; speedup 1.0000x reference)
//
#include <hip/hip_runtime.h>
#include <hip/hip_bf16.h>

// RWKV TimeMixing: N=8, T=2048, C=1024.
// Pipeline: 3x (mix + GEMM_bt) -> chunked stabilized wkv scan (3 kernels) -> GEMM_bt.

typedef float f4 __attribute__((ext_vector_type(4)));
typedef short bh8 __attribute__((ext_vector_type(8)));

__device__ __forceinline__ unsigned int cvt2bf(float a, float b) {
    __hip_bfloat162 h = __float22bfloat162_rn(make_float2(a, b));
    unsigned int u;
    __builtin_memcpy(&u, &h, 4);
    return u;
}

// C = A(M,K) @ W(N,K)^T, M=16384, N=K=1024. 128x128 tile, BK=32, 16x16x32 bf16 MFMA.
// DO_MIX: A(m,c) = lastx(n,c) + (x(m,c)-lastx(n,c))*mix(c). DO_SIG: sigmoid epilogue.
template <bool DO_MIX, bool DO_SIG>
__global__ __launch_bounds__(256, 2) void gemm_bt(
    const float* __restrict__ A, const float* __restrict__ W,
    const float* __restrict__ mix, const float* __restrict__ lastx,
    float* __restrict__ Y)
{
    // stride 56 shorts = 112B: 16B-aligned rows, 2-way-max bank aliasing on b128 reads
    __shared__ __align__(16) short As[128 * 56];
    __shared__ __align__(16) short Bs[128 * 56];

    const int tid = threadIdx.x;
    const int m0 = blockIdx.x * 128;
    const int n0 = blockIdx.y * 128;
    const int batch = m0 >> 11;           // T=2048 rows per batch; 128 | 2048
    const int lane = tid & 63;
    const int wv = tid >> 6;
    const int wm = (wv & 1) * 64;
    const int wn = (wv >> 1) * 64;
    const int fr = lane & 15;
    const int ko = (lane >> 4) * 8;

    const int r0 = tid >> 3;              // staging row base
    const int c4 = (tid & 7) * 4;         // staging col (floats)

    f4 acc[4][4];
#pragma unroll
    for (int i = 0; i < 4; i++)
#pragma unroll
        for (int j = 0; j < 4; j++) {
            f4 z = {0.f, 0.f, 0.f, 0.f};
            acc[i][j] = z;
        }

    for (int kk = 0; kk < 1024; kk += 32) {
        // issue global loads early (overlap with prior MFMA + barrier)
        f4 av[4], wv4[4], mv, lx;
        if (DO_MIX) {
            mv = *(const f4*)(mix + kk + c4);
            lx = *(const f4*)(lastx + batch * 1024 + kk + c4);
        }
#pragma unroll
        for (int it = 0; it < 4; ++it) {
            int row = it * 32 + r0;
            av[it] = *(const f4*)(A + (size_t)(m0 + row) * 1024 + kk + c4);
            wv4[it] = *(const f4*)(W + (size_t)(n0 + row) * 1024 + kk + c4);
        }
        __syncthreads();   // previous iteration's LDS reads complete
#pragma unroll
        for (int it = 0; it < 4; ++it) {
            int row = it * 32 + r0;
            f4 a = av[it];
            if (DO_MIX) a = lx + (a - lx) * mv;
            uint2 pa = make_uint2(cvt2bf(a.x, a.y), cvt2bf(a.z, a.w));
            *(uint2*)(&As[row * 56 + c4]) = pa;
            f4 ww = wv4[it];
            uint2 pb = make_uint2(cvt2bf(ww.x, ww.y), cvt2bf(ww.z, ww.w));
            *(uint2*)(&Bs[row * 56 + c4]) = pb;
        }
        __syncthreads();
        bh8 af[4], bf[4];
#pragma unroll
        for (int i = 0; i < 4; i++) af[i] = *(const bh8*)(&As[(wm + i * 16 + fr) * 56 + ko]);
#pragma unroll
        for (int j = 0; j < 4; j++) bf[j] = *(const bh8*)(&Bs[(wn + j * 16 + fr) * 56 + ko]);
#pragma unroll
        for (int i = 0; i < 4; i++)
#pragma unroll
            for (int j = 0; j < 4; j++)
                acc[i][j] = __builtin_amdgcn_mfma_f32_16x16x32_bf16(af[i], bf[j], acc[i][j], 0, 0, 0);
    }

    // epilogue: C/D layout col=lane&15, row=(lane>>4)*4+reg
    const int rbase = (lane >> 4) * 4;
#pragma unroll
    for (int i = 0; i < 4; i++)
#pragma unroll
        for (int j = 0; j < 4; j++)
#pragma unroll
            for (int r = 0; r < 4; r++) {
                float v = acc[i][j][r];
                if (DO_SIG) v = __fdividef(1.0f, 1.0f + __expf(-v));
                int row = m0 + wm + i * 16 + rbase + r;
                int col = n0 + wn + j * 16 + fr;
                Y[(size_t)row * 1024 + col] = v;
            }
}

// ---- chunked wkv scan: T=2048 = 32 chunks x 64 ----
// state kept as (a, b, e): true A = a*exp(e), B = b*exp(e); decay is e -= w per step.

__global__ __launch_bounds__(256) void wkv_pass1(
    const float* __restrict__ Kp, const float* __restrict__ Vp,
    const float* __restrict__ tdec,
    float* __restrict__ Ca, float* __restrict__ Cb, float* __restrict__ Ce)
{
    int tid = blockIdx.x * 256 + threadIdx.x;
    int c = tid & 1023;
    int chunk = (tid >> 10) & 31;
    int n = tid >> 15;
    float w = __expf(tdec[c]);
    int base = (n * 2048 + chunk * 64) * 1024 + c;
    float ca = 0.f, cb = 0.f, ce = -1e30f;
#pragma unroll 8
    for (int i = 0; i < 64; i++) {
        float kt = Kp[base + (i << 10)];
        float vt = Vp[base + (i << 10)];
        float ed = ce - w;
        float en = fmaxf(ed, kt);
        float f1 = __expf(ed - en);
        float f2 = __expf(kt - en);
        ca = fmaf(f1, ca, f2 * vt);
        cb = fmaf(f1, cb, f2);
        ce = en;
    }
    int oidx = ((n * 32 + chunk) << 10) + c;
    Ca[oidx] = ca; Cb[oidx] = cb; Ce[oidx] = ce;
}

__global__ __launch_bounds__(256) void wkv_pass2(
    const float* __restrict__ state, const float* __restrict__ tdec,
    const float* __restrict__ Ca, const float* __restrict__ Cb, const float* __restrict__ Ce,
    float* __restrict__ Sa, float* __restrict__ Sb, float* __restrict__ Se)
{
    int tid = blockIdx.x * 256 + threadIdx.x;   // 8192 threads
    int c = tid & 1023;
    int n = tid >> 10;
    float a = state[(n * 3 + 0) * 1024 + c];
    float b = state[(n * 3 + 1) * 1024 + c];
    float e = state[(n * 3 + 2) * 1024 + c];
    float wL = __expf(tdec[c]) * 64.0f;
    for (int ch = 0; ch < 32; ++ch) {
        int idx = ((n * 32 + ch) << 10) + c;
        Sa[idx] = a; Sb[idx] = b; Se[idx] = e;
        float ce = Ce[idx];
        float ed = e - wL;
        float en = fmaxf(ed, ce);
        float f1 = __expf(ed - en);
        float f2 = __expf(ce - en);
        a = fmaf(f1, a, f2 * Ca[idx]);
        b = fmaf(f1, b, f2 * Cb[idx]);
        e = en;
    }
}

// Pp may alias Kp (in-place). Manual D=4 rolling prefetch keeps loads ahead of stores.
__global__ __launch_bounds__(256) void wkv_pass3(
    const float* Kp, const float* __restrict__ Vp, const float* __restrict__ SRp,
    const float* __restrict__ Sa, const float* __restrict__ Sb, const float* __restrict__ Se,
    const float* __restrict__ tfirst, const float* __restrict__ tdec,
    float* Pp)
{
    int tid = blockIdx.x * 256 + threadIdx.x;
    int c = tid & 1023;
    int chunk = (tid >> 10) & 31;
    int n = tid >> 15;
    int sidx = ((n * 32 + chunk) << 10) + c;
    float a = Sa[sidx], b = Sb[sidx], e = Se[sidx];
    float u = tfirst[c];
    float w = __expf(tdec[c]);
    int base = (n * 2048 + chunk * 64) * 1024 + c;
    float kb[4], vb[4], sb[4];
#pragma unroll
    for (int i = 0; i < 4; i++) {
        kb[i] = Kp[base + (i << 10)];
        vb[i] = Vp[base + (i << 10)];
        sb[i] = SRp[base + (i << 10)];
    }
#pragma unroll
    for (int i = 0; i < 64; i++) {
        float kt = kb[i & 3], vt = vb[i & 3], st = sb[i & 3];
        if (i + 4 < 64) {
            int a2 = base + ((i + 4) << 10);
            kb[i & 3] = Kp[a2]; vb[i & 3] = Vp[a2]; sb[i & 3] = SRp[a2];
        }
        float ukt = u + kt;
        float tau = fmaxf(ukt, e);
        float e1 = __expf(e - tau);
        float e2 = __expf(ukt - tau);
        float wkv = __fdividef(fmaf(e1, a, e2 * vt), fmaf(e1, b, e2));
        Pp[base + (i << 10)] = wkv * st;
        float ed = e - w;
        float en = fmaxf(ed, kt);
        float f1 = __expf(ed - en);
        float f2 = __expf(kt - en);
        a = fmaf(f1, a, f2 * vt);
        b = fmaf(f1, b, f2);
        e = en;
    }
}

extern "C" void kernel_launch(void* const* d_in, const int* in_sizes, int n_in,
                              void* d_out, int out_size, void* d_ws, size_t ws_size,
                              hipStream_t stream) {
    const float* x      = (const float*)d_in[0];
    // d_in[1] = it (unused)
    const float* Wk     = (const float*)d_in[2];
    const float* Wv     = (const float*)d_in[3];
    const float* Wr     = (const float*)d_in[4];
    const float* Wo     = (const float*)d_in[5];
    const float* tmk    = (const float*)d_in[6];
    const float* tmv    = (const float*)d_in[7];
    const float* tmr    = (const float*)d_in[8];
    const float* tdec   = (const float*)d_in[9];
    const float* tfirst = (const float*)d_in[10];
    const float* lastx  = (const float*)d_in[11];
    const float* state  = (const float*)d_in[12];
    float* out = (float*)d_out;

    char* ws = (char*)d_ws;
    float* K  = (float*)(ws);                      // 64 MB
    float* V  = (float*)(ws + 67108864ull);        // 64 MB
    float* SR = (float*)(ws + 134217728ull);       // 64 MB
    float* Ca = (float*)(ws + 201326592ull);       // 1 MB each
    float* Cb = Ca + 262144;
    float* Ce = Cb + 262144;
    float* Sa = Ce + 262144;
    float* Sb = Sa + 262144;
    float* Se = Sb + 262144;
    // P: separate region if workspace allows, else alias K (in-place, correct either way)
    float* P = (ws_size >= 274726912ull) ? (float*)(ws + 207618048ull) : K;

    dim3 g(128, 8), b(256);
    gemm_bt<true,  false><<<g, b, 0, stream>>>(x, Wk, tmk, lastx, K);
    gemm_bt<true,  false><<<g, b, 0, stream>>>(x, Wv, tmv, lastx, V);
    gemm_bt<true,  true ><<<g, b, 0, stream>>>(x, Wr, tmr, lastx, SR);
    wkv_pass1<<<1024, 256, 0, stream>>>(K, V, tdec, Ca, Cb, Ce);
    wkv_pass2<<<32, 256, 0, stream>>>(state, tdec, Ca, Cb, Ce, Sa, Sb, Se);
    wkv_pass3<<<1024, 256, 0, stream>>>(K, V, SR, Sa, Sb, Se, tfirst, tdec, P);
    gemm_bt<false, false><<<g, b, 0, stream>>>(P, Wo, nullptr, nullptr, out);
}

// Round 2
// 392.483 us; speedup vs baseline: 1.4649x; 1.4649x over previous
//
#include <hip/hip_runtime.h>
#include <hip/hip_bf16.h>
#include <stdint.h>

// RWKV TimeMixing: N=8, T=2048, C=1024.
// prep(mix->bf16) + convw -> 3x m97-style bf16 GEMM -> chunked wkv scan (bf16 I/O, f32 math) -> bf16 GEMM.

typedef float f4 __attribute__((ext_vector_type(4)));
typedef short bh8 __attribute__((ext_vector_type(8)));
typedef unsigned int u32;
typedef unsigned short u16;

__device__ __forceinline__ u32 cvt2bf(float a, float b) {
    __hip_bfloat162 h = __float22bfloat162_rn(make_float2(a, b));
    u32 u; __builtin_memcpy(&u, &h, 4); return u;
}
__device__ __forceinline__ float b2f(u16 u) {
    u32 x = (u32)u << 16; float f; __builtin_memcpy(&f, &x, 4); return f;
}
__device__ __forceinline__ u16 f2b(float f) {
    __hip_bfloat16 h = __float2bfloat16(f);
    u16 u; __builtin_memcpy(&u, &h, 2); return u;
}
__device__ __forceinline__ void gld_lds16(const void* g, void* l) {
    __builtin_amdgcn_global_load_lds(
        (const __attribute__((address_space(1))) u32*)g,
        (__attribute__((address_space(3))) u32*)l, 16, 0, 0);
}

// ---------------- GEMM: Y(M,N) = A(M,K) @ B(N,K)^T, bf16 in, M=16384 N=K=1024 ----------------
// 128x128 tile, BK=32, 4 waves each 64x64 (4x4 MFMA 16x16x32).
// Staging: global_load_lds width16; LDS rows 64B unpadded (required by lane-contig dest);
// bank conflicts broken by XOR-swizzling the 16B chunks at the GLOBAL source:
//   chunk c of row r lands in LDS slot p = c ^ ((r>>1)&3)  ->  2-way max on ds_read_b128 (free).
// EPI: 0 = f32 store, 1 = bf16 store, 2 = sigmoid + bf16 store.
template <int EPI>
__global__ __launch_bounds__(256, 2) void gemm_bt(
    const u16* __restrict__ A, const u16* __restrict__ B, void* __restrict__ Yv)
{
    __shared__ __align__(16) u16 As[128 * 32];
    __shared__ __align__(16) u16 Bs[128 * 32];

    const int tid  = threadIdx.x;
    const int w    = tid >> 6;
    const int lane = tid & 63;
    const int m0 = blockIdx.x * 128;
    const int n0 = blockIdx.y * 128;

    // --- staging geometry: wave w covers tile rows [w*32, w*32+32), 2 insts of 16 rows each
    const int srow = w * 32 + (lane >> 2);     // row for inst t=0 (t=1: +16, same swizzle phase)
    const int slot = lane & 3;                  // LDS 16B slot within the 64B row
    const int chk  = slot ^ ((srow >> 1) & 3);  // source chunk (XOR swizzle)
    const u16* gA0 = A + (size_t)(m0 + srow) * 1024 + chk * 8;
    const u16* gA1 = gA0 + (size_t)16 * 1024;
    const u16* gB0 = B + (size_t)(n0 + srow) * 1024 + chk * 8;
    const u16* gB1 = gB0 + (size_t)16 * 1024;
    u16* lA0 = As + (w * 32) * 32;              // wave-uniform LDS bases
    u16* lA1 = lA0 + 16 * 32;
    u16* lB0 = Bs + (w * 32) * 32;
    u16* lB1 = lB0 + 16 * 32;

    // --- fragment geometry
    const int fr   = lane & 15;
    const int quad = lane >> 4;
    const int wm = (w & 1) * 64;
    const int wn = (w >> 1) * 64;
    const int sp = quad ^ ((fr >> 1) & 3);      // swizzled slot holding chunk `quad`
    const int aoff = (wm + fr) * 32 + sp * 8;
    const int boff = (wn + fr) * 32 + sp * 8;

    f4 acc[4][4];
#pragma unroll
    for (int i = 0; i < 4; i++)
#pragma unroll
        for (int j = 0; j < 4; j++) { f4 z = {0.f, 0.f, 0.f, 0.f}; acc[i][j] = z; }

    for (int kk = 0; kk < 1024; kk += 32) {
        gld_lds16(gA0 + kk, lA0);
        gld_lds16(gA1 + kk, lA1);
        gld_lds16(gB0 + kk, lB0);
        gld_lds16(gB1 + kk, lB1);
        __syncthreads();                        // drains vmcnt (staging complete)
        bh8 af[4], bf[4];
#pragma unroll
        for (int i = 0; i < 4; i++) af[i] = *(const bh8*)(As + aoff + i * 16 * 32);
#pragma unroll
        for (int j = 0; j < 4; j++) bf[j] = *(const bh8*)(Bs + boff + j * 16 * 32);
#pragma unroll
        for (int i = 0; i < 4; i++)
#pragma unroll
            for (int j = 0; j < 4; j++)
                acc[i][j] = __builtin_amdgcn_mfma_f32_16x16x32_bf16(af[i], bf[j], acc[i][j], 0, 0, 0);
        __syncthreads();                        // frag reads done before next overwrite
    }

    // epilogue: C/D layout col=lane&15, row=(lane>>4)*4+reg
    const int rb = quad * 4;
#pragma unroll
    for (int i = 0; i < 4; i++)
#pragma unroll
        for (int j = 0; j < 4; j++)
#pragma unroll
            for (int r = 0; r < 4; r++) {
                float v = acc[i][j][r];
                size_t row = (size_t)(m0 + wm + i * 16 + rb + r);
                size_t col = (size_t)(n0 + wn + j * 16 + fr);
                if (EPI == 0) {
                    ((float*)Yv)[row * 1024 + col] = v;
                } else if (EPI == 1) {
                    ((u16*)Yv)[row * 1024 + col] = f2b(v);
                } else {
                    ((u16*)Yv)[row * 1024 + col] = f2b(__fdividef(1.0f, 1.0f + __expf(-v)));
                }
            }
}

// ---------------- prep: fused time-mix + f32->bf16 for all three projections ----------------
__global__ __launch_bounds__(256) void prep3(
    const float* __restrict__ x, const float* __restrict__ lastx,
    const float* __restrict__ tmk, const float* __restrict__ tmv, const float* __restrict__ tmr,
    u16* __restrict__ Xk, u16* __restrict__ Xv, u16* __restrict__ Xr)
{
    int idx = blockIdx.x * 256 + threadIdx.x;   // 4M f4 units
    int e = idx << 2;
    int c = e & 1023;
    int n = e >> 21;
    f4 xv = *(const f4*)(x + e);
    f4 lx = *(const f4*)(lastx + (n << 10) + c);
    f4 mk = *(const f4*)(tmk + c);
    f4 mv = *(const f4*)(tmv + c);
    f4 mr = *(const f4*)(tmr + c);
    f4 k = lx + (xv - lx) * mk;
    f4 v = lx + (xv - lx) * mv;
    f4 r = lx + (xv - lx) * mr;
    *(uint2*)(Xk + e) = make_uint2(cvt2bf(k.x, k.y), cvt2bf(k.z, k.w));
    *(uint2*)(Xv + e) = make_uint2(cvt2bf(v.x, v.y), cvt2bf(v.z, v.w));
    *(uint2*)(Xr + e) = make_uint2(cvt2bf(r.x, r.y), cvt2bf(r.z, r.w));
}

// single-output variant (small-workspace fallback)
__global__ __launch_bounds__(256) void prep1(
    const float* __restrict__ x, const float* __restrict__ lastx,
    const float* __restrict__ tm, u16* __restrict__ X)
{
    int idx = blockIdx.x * 256 + threadIdx.x;
    int e = idx << 2;
    int c = e & 1023;
    int n = e >> 21;
    f4 xv = *(const f4*)(x + e);
    f4 lx = *(const f4*)(lastx + (n << 10) + c);
    f4 m  = *(const f4*)(tm + c);
    f4 k = lx + (xv - lx) * m;
    *(uint2*)(X + e) = make_uint2(cvt2bf(k.x, k.y), cvt2bf(k.z, k.w));
}

__global__ __launch_bounds__(256) void convw(const float* __restrict__ s, u16* __restrict__ d) {
    int idx = blockIdx.x * 256 + threadIdx.x;   // 256K f4 units (1M elements)
    int e = idx << 2;
    f4 v = *(const f4*)(s + e);
    *(uint2*)(d + e) = make_uint2(cvt2bf(v.x, v.y), cvt2bf(v.z, v.w));
}

// ---------------- chunked wkv scan: T=2048 = 32 chunks x 64, bf16 k/v/sr, f32 math ----------------
__global__ __launch_bounds__(256) void wkv_pass1(
    const u16* __restrict__ Kp, const u16* __restrict__ Vp,
    const float* __restrict__ tdec,
    float* __restrict__ Ca, float* __restrict__ Cb, float* __restrict__ Ce)
{
    int tid = blockIdx.x * 256 + threadIdx.x;
    int c = tid & 1023;
    int chunk = (tid >> 10) & 31;
    int n = tid >> 15;
    float w = __expf(tdec[c]);
    int base = (n * 2048 + chunk * 64) * 1024 + c;
    float ca = 0.f, cb = 0.f, ce = -1e30f;
#pragma unroll 8
    for (int i = 0; i < 64; i++) {
        float kt = b2f(Kp[base + (i << 10)]);
        float vt = b2f(Vp[base + (i << 10)]);
        float ed = ce - w;
        float en = fmaxf(ed, kt);
        float f1 = __expf(ed - en);
        float f2 = __expf(kt - en);
        ca = fmaf(f1, ca, f2 * vt);
        cb = fmaf(f1, cb, f2);
        ce = en;
    }
    int oidx = ((n * 32 + chunk) << 10) + c;
    Ca[oidx] = ca; Cb[oidx] = cb; Ce[oidx] = ce;
}

__global__ __launch_bounds__(256) void wkv_pass2(
    const float* __restrict__ state, const float* __restrict__ tdec,
    const float* __restrict__ Ca, const float* __restrict__ Cb, const float* __restrict__ Ce,
    float* __restrict__ Sa, float* __restrict__ Sb, float* __restrict__ Se)
{
    int tid = blockIdx.x * 256 + threadIdx.x;   // 8192 threads
    int c = tid & 1023;
    int n = tid >> 10;
    float a = state[(n * 3 + 0) * 1024 + c];
    float b = state[(n * 3 + 1) * 1024 + c];
    float e = state[(n * 3 + 2) * 1024 + c];
    float wL = __expf(tdec[c]) * 64.0f;
    for (int ch = 0; ch < 32; ++ch) {
        int idx = ((n * 32 + ch) << 10) + c;
        Sa[idx] = a; Sb[idx] = b; Se[idx] = e;
        float ce = Ce[idx];
        float ed = e - wL;
        float en = fmaxf(ed, ce);
        float f1 = __expf(ed - en);
        float f2 = __expf(ce - en);
        a = fmaf(f1, a, f2 * Ca[idx]);
        b = fmaf(f1, b, f2 * Cb[idx]);
        e = en;
    }
}

__global__ __launch_bounds__(256) void wkv_pass3(
    const u16* __restrict__ Kp, const u16* __restrict__ Vp, const u16* __restrict__ SRp,
    const float* __restrict__ Sa, const float* __restrict__ Sb, const float* __restrict__ Se,
    const float* __restrict__ tfirst, const float* __restrict__ tdec,
    u16* __restrict__ Pp)
{
    int tid = blockIdx.x * 256 + threadIdx.x;
    int c = tid & 1023;
    int chunk = (tid >> 10) & 31;
    int n = tid >> 15;
    int sidx = ((n * 32 + chunk) << 10) + c;
    float a = Sa[sidx], b = Sb[sidx], e = Se[sidx];
    float u = tfirst[c];
    float w = __expf(tdec[c]);
    int base = (n * 2048 + chunk * 64) * 1024 + c;
#pragma unroll 4
    for (int i = 0; i < 64; i++) {
        float kt = b2f(Kp[base + (i << 10)]);
        float vt = b2f(Vp[base + (i << 10)]);
        float st = b2f(SRp[base + (i << 10)]);
        float ukt = u + kt;
        float tau = fmaxf(ukt, e);
        float e1 = __expf(e - tau);
        float e2 = __expf(ukt - tau);
        float wkv = __fdividef(fmaf(e1, a, e2 * vt), fmaf(e1, b, e2));
        Pp[base + (i << 10)] = f2b(wkv * st);
        float ed = e - w;
        float en = fmaxf(ed, kt);
        float f1 = __expf(ed - en);
        float f2 = __expf(kt - en);
        a = fmaf(f1, a, f2 * vt);
        b = fmaf(f1, b, f2);
        e = en;
    }
}

extern "C" void kernel_launch(void* const* d_in, const int* in_sizes, int n_in,
                              void* d_out, int out_size, void* d_ws, size_t ws_size,
                              hipStream_t stream) {
    const float* x      = (const float*)d_in[0];
    const float* Wk     = (const float*)d_in[2];
    const float* Wv     = (const float*)d_in[3];
    const float* Wr     = (const float*)d_in[4];
    const float* Wo     = (const float*)d_in[5];
    const float* tmk    = (const float*)d_in[6];
    const float* tmv    = (const float*)d_in[7];
    const float* tmr    = (const float*)d_in[8];
    const float* tdec   = (const float*)d_in[9];
    const float* tfirst = (const float*)d_in[10];
    const float* lastx  = (const float*)d_in[11];
    const float* state  = (const float*)d_in[12];
    float* out = (float*)d_out;

    const size_t MB = 1024ull * 1024ull;
    char* ws = (char*)d_ws;
    u16* Kb  = (u16*)(ws);                 // 32 MB
    u16* Vb  = (u16*)(ws + 32 * MB);       // 32 MB
    u16* SRb = (u16*)(ws + 64 * MB);       // 32 MB

    dim3 g(128, 8), blk(256);
    const bool big = ws_size >= 206 * MB;

    if (big) {
        u16* Xk  = (u16*)(ws + 96 * MB);
        u16* Xv  = (u16*)(ws + 128 * MB);
        u16* Xr  = (u16*)(ws + 160 * MB);
        u16* Wkb = (u16*)(ws + 192 * MB);
        u16* Wvb = (u16*)(ws + 194 * MB);
        u16* Wrb = (u16*)(ws + 196 * MB);
        u16* Wob = (u16*)(ws + 198 * MB);
        float* Ca = (float*)(ws + 200 * MB);
        float* Cb = Ca + 262144;
        float* Ce = Cb + 262144;
        float* Sa = Ce + 262144;
        float* Sb = Sa + 262144;
        float* Se = Sb + 262144;
        u16* Pb = Xk;  // Xk dead after its GEMM

        prep3<<<16384, blk, 0, stream>>>(x, lastx, tmk, tmv, tmr, Xk, Xv, Xr);
        convw<<<1024, blk, 0, stream>>>(Wk, Wkb);
        convw<<<1024, blk, 0, stream>>>(Wv, Wvb);
        convw<<<1024, blk, 0, stream>>>(Wr, Wrb);
        convw<<<1024, blk, 0, stream>>>(Wo, Wob);
        gemm_bt<1><<<g, blk, 0, stream>>>(Xk, Wkb, Kb);
        gemm_bt<1><<<g, blk, 0, stream>>>(Xv, Wvb, Vb);
        gemm_bt<2><<<g, blk, 0, stream>>>(Xr, Wrb, SRb);
        wkv_pass1<<<1024, blk, 0, stream>>>(Kb, Vb, tdec, Ca, Cb, Ce);
        wkv_pass2<<<32, blk, 0, stream>>>(state, tdec, Ca, Cb, Ce, Sa, Sb, Se);
        wkv_pass3<<<1024, blk, 0, stream>>>(Kb, Vb, SRb, Sa, Sb, Se, tfirst, tdec, Pb);
        gemm_bt<0><<<g, blk, 0, stream>>>(Pb, Wob, out);
    } else {
        u16* X   = (u16*)(ws + 96 * MB);   // shared mixed-input buffer, 32 MB
        u16* Wkb = (u16*)(ws + 128 * MB);
        u16* Wvb = (u16*)(ws + 130 * MB);
        u16* Wrb = (u16*)(ws + 132 * MB);
        u16* Wob = (u16*)(ws + 134 * MB);
        float* Ca = (float*)(ws + 136 * MB);
        float* Cb = Ca + 262144;
        float* Ce = Cb + 262144;
        float* Sa = Ce + 262144;
        float* Sb = Sa + 262144;
        float* Se = Sb + 262144;
        u16* Pb = X;

        convw<<<1024, blk, 0, stream>>>(Wk, Wkb);
        convw<<<1024, blk, 0, stream>>>(Wv, Wvb);
        convw<<<1024, blk, 0, stream>>>(Wr, Wrb);
        convw<<<1024, blk, 0, stream>>>(Wo, Wob);
        prep1<<<16384, blk, 0, stream>>>(x, lastx, tmk, X);
        gemm_bt<1><<<g, blk, 0, stream>>>(X, Wkb, Kb);
        prep1<<<16384, blk, 0, stream>>>(x, lastx, tmv, X);
        gemm_bt<1><<<g, blk, 0, stream>>>(X, Wvb, Vb);
        prep1<<<16384, blk, 0, stream>>>(x, lastx, tmr, X);
        gemm_bt<2><<<g, blk, 0, stream>>>(X, Wrb, SRb);
        wkv_pass1<<<1024, blk, 0, stream>>>(Kb, Vb, tdec, Ca, Cb, Ce);
        wkv_pass2<<<32, blk, 0, stream>>>(state, tdec, Ca, Cb, Ce, Sa, Sb, Se);
        wkv_pass3<<<1024, blk, 0, stream>>>(Kb, Vb, SRb, Sa, Sb, Se, tfirst, tdec, Pb);
        gemm_bt<0><<<g, blk, 0, stream>>>(Pb, Wob, out);
    }
}

// Round 3
// 377.272 us; speedup vs baseline: 1.5239x; 1.0403x over previous
//
#include <hip/hip_runtime.h>
#include <hip/hip_bf16.h>
#include <stdint.h>

// RWKV TimeMixing: N=8, T=2048, C=1024.
// Round 3: lastx folded into per-batch bias (mix is affine, lastx broadcasts over T):
//   k = x @ (mk.Wk)^T + lastx @ ((1-mk).Wk)^T   (bias is 8x1024, computed in f32)
// Pipeline: convx + prepw + bias3 -> merged KVR bf16 GEMM (1 dispatch, bias+sigmoid epilogue)
//           -> chunked wkv scan (ushort2-vectorized) -> bf16 GEMM -> f32 out.

typedef float f4 __attribute__((ext_vector_type(4)));
typedef short bh8 __attribute__((ext_vector_type(8)));
typedef unsigned int u32;
typedef unsigned short u16;

__device__ __forceinline__ u32 cvt2bf(float a, float b) {
    __hip_bfloat162 h = __float22bfloat162_rn(make_float2(a, b));
    u32 u; __builtin_memcpy(&u, &h, 4); return u;
}
__device__ __forceinline__ float b2f(u16 u) {
    u32 x = (u32)u << 16; float f; __builtin_memcpy(&f, &x, 4); return f;
}
__device__ __forceinline__ u16 f2b(float f) {
    __hip_bfloat16 h = __float2bfloat16(f);
    u16 u; __builtin_memcpy(&u, &h, 2); return u;
}
__device__ __forceinline__ void gld_lds16(const void* g, void* l) {
    __builtin_amdgcn_global_load_lds(
        (const __attribute__((address_space(1))) u32*)g,
        (__attribute__((address_space(3))) u32*)l, 16, 0, 0);
}

// ---------------- shared GEMM mainloop: acc += A(m0:128,:) @ B(n0:128,:)^T, K=1024, BK=32 ----
// Staging via global_load_lds w16; bank conflicts broken by XOR-swizzling 16B chunks at the
// GLOBAL source (chunk c of row r -> LDS slot c ^ ((r>>1)&3)); proven 0-conflict in R2.
__device__ __forceinline__ void gemm_core(
    const u16* __restrict__ A, const u16* __restrict__ B,
    int m0, int n0, u16* As, u16* Bs, f4 (&acc)[4][4])
{
    const int tid  = threadIdx.x;
    const int w    = tid >> 6;
    const int lane = tid & 63;

    const int srow = w * 32 + (lane >> 2);
    const int slot = lane & 3;
    const int chk  = slot ^ ((srow >> 1) & 3);
    const u16* gA0 = A + (size_t)(m0 + srow) * 1024 + chk * 8;
    const u16* gA1 = gA0 + (size_t)16 * 1024;
    const u16* gB0 = B + (size_t)(n0 + srow) * 1024 + chk * 8;
    const u16* gB1 = gB0 + (size_t)16 * 1024;
    u16* lA0 = As + (w * 32) * 32;
    u16* lA1 = lA0 + 16 * 32;
    u16* lB0 = Bs + (w * 32) * 32;
    u16* lB1 = lB0 + 16 * 32;

    const int fr   = lane & 15;
    const int quad = lane >> 4;
    const int wm = (w & 1) * 64;
    const int wn = (w >> 1) * 64;
    const int sp = quad ^ ((fr >> 1) & 3);
    const int aoff = (wm + fr) * 32 + sp * 8;
    const int boff = (wn + fr) * 32 + sp * 8;

    for (int kk = 0; kk < 1024; kk += 32) {
        gld_lds16(gA0 + kk, lA0);
        gld_lds16(gA1 + kk, lA1);
        gld_lds16(gB0 + kk, lB0);
        gld_lds16(gB1 + kk, lB1);
        __syncthreads();
        bh8 af[4], bf[4];
#pragma unroll
        for (int i = 0; i < 4; i++) af[i] = *(const bh8*)(As + aoff + i * 16 * 32);
#pragma unroll
        for (int j = 0; j < 4; j++) bf[j] = *(const bh8*)(Bs + boff + j * 16 * 32);
#pragma unroll
        for (int i = 0; i < 4; i++)
#pragma unroll
            for (int j = 0; j < 4; j++)
                acc[i][j] = __builtin_amdgcn_mfma_f32_16x16x32_bf16(af[i], bf[j], acc[i][j], 0, 0, 0);
        __syncthreads();
    }
}

// Merged K/V/R GEMM. grid (128, 24): blockIdx.y -> proj = y>>3, local n0 = (y&7)*128.
// Epilogue: + bias[proj][batch][col]; proj==2 applies sigmoid; bf16 stores.
__global__ __launch_bounds__(256, 2) void gemm_kvr(
    const u16* __restrict__ A, const u16* __restrict__ Wall, const float* __restrict__ bias,
    u16* __restrict__ Kb, u16* __restrict__ Vb, u16* __restrict__ SRb)
{
    __shared__ __align__(16) u16 As[128 * 32];
    __shared__ __align__(16) u16 Bs[128 * 32];
    const int m0 = blockIdx.x * 128;
    const int proj = blockIdx.y >> 3;
    const int n0 = (blockIdx.y & 7) * 128;
    const u16* B = Wall + (size_t)proj * 1048576;

    f4 acc[4][4];
#pragma unroll
    for (int i = 0; i < 4; i++)
#pragma unroll
        for (int j = 0; j < 4; j++) { f4 z = {0.f, 0.f, 0.f, 0.f}; acc[i][j] = z; }
    gemm_core(A, B, m0, n0, As, Bs, acc);

    u16* Y = proj == 0 ? Kb : (proj == 1 ? Vb : SRb);
    const int lane = threadIdx.x & 63;
    const int w = threadIdx.x >> 6;
    const int fr = lane & 15, quad = lane >> 4;
    const int wm = (w & 1) * 64, wn = (w >> 1) * 64;
    const int rb = quad * 4;
    const int batch = m0 >> 11;                 // 2048 rows per batch; m0 tile stays in one batch
    float bv[4];
#pragma unroll
    for (int j = 0; j < 4; j++) bv[j] = bias[proj * 8192 + batch * 1024 + n0 + wn + j * 16 + fr];
#pragma unroll
    for (int i = 0; i < 4; i++)
#pragma unroll
        for (int j = 0; j < 4; j++)
#pragma unroll
            for (int r = 0; r < 4; r++) {
                float v = acc[i][j][r] + bv[j];
                if (proj == 2) v = __fdividef(1.0f, 1.0f + __expf(-v));
                size_t row = (size_t)(m0 + wm + i * 16 + rb + r);
                size_t col = (size_t)(n0 + wn + j * 16 + fr);
                Y[row * 1024 + col] = f2b(v);
            }
}

// Output GEMM: out(16384,1024) f32 = P @ Wo^T
__global__ __launch_bounds__(256, 2) void gemm_out(
    const u16* __restrict__ A, const u16* __restrict__ B, float* __restrict__ Y)
{
    __shared__ __align__(16) u16 As[128 * 32];
    __shared__ __align__(16) u16 Bs[128 * 32];
    const int m0 = blockIdx.x * 128;
    const int n0 = blockIdx.y * 128;
    f4 acc[4][4];
#pragma unroll
    for (int i = 0; i < 4; i++)
#pragma unroll
        for (int j = 0; j < 4; j++) { f4 z = {0.f, 0.f, 0.f, 0.f}; acc[i][j] = z; }
    gemm_core(A, B, m0, n0, As, Bs, acc);

    const int lane = threadIdx.x & 63;
    const int w = threadIdx.x >> 6;
    const int fr = lane & 15, quad = lane >> 4;
    const int wm = (w & 1) * 64, wn = (w >> 1) * 64;
    const int rb = quad * 4;
#pragma unroll
    for (int i = 0; i < 4; i++)
#pragma unroll
        for (int j = 0; j < 4; j++)
#pragma unroll
            for (int r = 0; r < 4; r++) {
                size_t row = (size_t)(m0 + wm + i * 16 + rb + r);
                size_t col = (size_t)(n0 + wn + j * 16 + fr);
                Y[row * 1024 + col] = acc[i][j][r];
            }
}

// ---------------- prep kernels ----------------
__global__ __launch_bounds__(256) void convx(const float* __restrict__ s, u16* __restrict__ d) {
    int idx = blockIdx.x * 256 + threadIdx.x;   // 4M f4 units
    int e = idx << 2;
    f4 v = *(const f4*)(s + e);
    *(uint2*)(d + e) = make_uint2(cvt2bf(v.x, v.y), cvt2bf(v.z, v.w));
}

// Wall[proj] = bf16(mix_proj[c] * Wproj[n,c]) for proj<3; Wall[3] = bf16(Wo).
__global__ __launch_bounds__(256) void prepw(
    const float* __restrict__ Wk, const float* __restrict__ Wv,
    const float* __restrict__ Wr, const float* __restrict__ Wo,
    const float* __restrict__ tmk, const float* __restrict__ tmv, const float* __restrict__ tmr,
    u16* __restrict__ Wall)
{
    int idx = blockIdx.x * 256 + threadIdx.x;   // 1M f4 units (4M elements)
    int e = idx << 2;
    int wid = e >> 20;
    int off = e & 1048575;
    int c = e & 1023;
    const float* src = wid == 0 ? Wk : (wid == 1 ? Wv : (wid == 2 ? Wr : Wo));
    f4 v = *(const f4*)(src + off);
    if (wid < 3) {
        const float* m = wid == 0 ? tmk : (wid == 1 ? tmv : tmr);
        v = v * *(const f4*)(m + c);
    }
    *(uint2*)(Wall + e) = make_uint2(cvt2bf(v.x, v.y), cvt2bf(v.z, v.w));
}

// bias[proj][b][n] = sum_c lastx[b,c] * (1-mix_proj[c]) * Wproj[n,c]   (all f32, exact path)
__global__ __launch_bounds__(256) void bias3(
    const float* __restrict__ Wk, const float* __restrict__ Wv, const float* __restrict__ Wr,
    const float* __restrict__ tmk, const float* __restrict__ tmv, const float* __restrict__ tmr,
    const float* __restrict__ lastx, float* __restrict__ bias)
{
    int wid = blockIdx.x * 4 + (threadIdx.x >> 6);   // 3072 waves: (proj, n)
    int lane = threadIdx.x & 63;
    int proj = wid >> 10;
    int n = wid & 1023;
    const float* W = proj == 0 ? Wk : (proj == 1 ? Wv : Wr);
    const float* m = proj == 0 ? tmk : (proj == 1 ? tmv : tmr);
    float acc[8];
#pragma unroll
    for (int b = 0; b < 8; b++) acc[b] = 0.f;
    for (int c = lane; c < 1024; c += 64) {
        float wc = W[n * 1024 + c] * (1.0f - m[c]);
#pragma unroll
        for (int b = 0; b < 8; b++) acc[b] = fmaf(lastx[b * 1024 + c], wc, acc[b]);
    }
#pragma unroll
    for (int b = 0; b < 8; b++) {
        float v = acc[b];
#pragma unroll
        for (int sh = 32; sh >= 1; sh >>= 1) v += __shfl_xor(v, sh);
        if (lane == 0) bias[proj * 8192 + b * 1024 + n] = v;
    }
}

// ---------------- chunked wkv scan: T=2048 = 32 chunks x 64; 2 channels/thread ----------------
__global__ __launch_bounds__(256) void wkv_pass1(
    const u16* __restrict__ Kp, const u16* __restrict__ Vp,
    const float* __restrict__ tdec,
    float* __restrict__ Ca, float* __restrict__ Cb, float* __restrict__ Ce)
{
    int tid = blockIdx.x * 256 + threadIdx.x;   // 131072 threads
    int c = (tid & 511) << 1;
    int chunk = (tid >> 9) & 31;
    int n = tid >> 14;
    float w0 = __expf(tdec[c]), w1 = __expf(tdec[c + 1]);
    int base = (n * 2048 + chunk * 64) * 1024 + c;
    float a0 = 0.f, b0 = 0.f, e0 = -1e30f;
    float a1 = 0.f, b1 = 0.f, e1 = -1e30f;
#pragma unroll 4
    for (int i = 0; i < 64; i++) {
        u32 ku = *(const u32*)(Kp + base + (i << 10));
        u32 vu = *(const u32*)(Vp + base + (i << 10));
        float k0 = b2f((u16)ku), k1 = b2f((u16)(ku >> 16));
        float v0 = b2f((u16)vu), v1 = b2f((u16)(vu >> 16));
        float en0 = fmaxf(e0 - w0, k0);
        float f10 = __expf(e0 - w0 - en0), f20 = __expf(k0 - en0);
        a0 = fmaf(f10, a0, f20 * v0); b0 = fmaf(f10, b0, f20); e0 = en0;
        float en1 = fmaxf(e1 - w1, k1);
        float f11 = __expf(e1 - w1 - en1), f21 = __expf(k1 - en1);
        a1 = fmaf(f11, a1, f21 * v1); b1 = fmaf(f11, b1, f21); e1 = en1;
    }
    int oidx = ((n * 32 + chunk) << 10) + c;
    *(float2*)(Ca + oidx) = make_float2(a0, a1);
    *(float2*)(Cb + oidx) = make_float2(b0, b1);
    *(float2*)(Ce + oidx) = make_float2(e0, e1);
}

__global__ __launch_bounds__(256) void wkv_pass2(
    const float* __restrict__ state, const float* __restrict__ tdec,
    const float* __restrict__ Ca, const float* __restrict__ Cb, const float* __restrict__ Ce,
    float* __restrict__ Sa, float* __restrict__ Sb, float* __restrict__ Se)
{
    int tid = blockIdx.x * 256 + threadIdx.x;   // 8192 threads
    int c = tid & 1023;
    int n = tid >> 10;
    float a = state[(n * 3 + 0) * 1024 + c];
    float b = state[(n * 3 + 1) * 1024 + c];
    float e = state[(n * 3 + 2) * 1024 + c];
    float wL = __expf(tdec[c]) * 64.0f;
    for (int ch = 0; ch < 32; ++ch) {
        int idx = ((n * 32 + ch) << 10) + c;
        Sa[idx] = a; Sb[idx] = b; Se[idx] = e;
        float ce = Ce[idx];
        float en = fmaxf(e - wL, ce);
        float f1 = __expf(e - wL - en);
        float f2 = __expf(ce - en);
        a = fmaf(f1, a, f2 * Ca[idx]);
        b = fmaf(f1, b, f2 * Cb[idx]);
        e = en;
    }
}

__global__ __launch_bounds__(256) void wkv_pass3(
    const u16* __restrict__ Kp, const u16* __restrict__ Vp, const u16* __restrict__ SRp,
    const float* __restrict__ Sa, const float* __restrict__ Sb, const float* __restrict__ Se,
    const float* __restrict__ tfirst, const float* __restrict__ tdec,
    u16* __restrict__ Pp)
{
    int tid = blockIdx.x * 256 + threadIdx.x;   // 131072 threads
    int c = (tid & 511) << 1;
    int chunk = (tid >> 9) & 31;
    int n = tid >> 14;
    int sidx = ((n * 32 + chunk) << 10) + c;
    float a0 = Sa[sidx], b0 = Sb[sidx], e0 = Se[sidx];
    float a1 = Sa[sidx + 1], b1 = Sb[sidx + 1], e1 = Se[sidx + 1];
    float u0 = tfirst[c], u1 = tfirst[c + 1];
    float w0 = __expf(tdec[c]), w1 = __expf(tdec[c + 1]);
    int base = (n * 2048 + chunk * 64) * 1024 + c;
#pragma unroll 2
    for (int i = 0; i < 64; i++) {
        u32 ku = *(const u32*)(Kp + base + (i << 10));
        u32 vu = *(const u32*)(Vp + base + (i << 10));
        u32 su = *(const u32*)(SRp + base + (i << 10));
        float k0 = b2f((u16)ku), k1 = b2f((u16)(ku >> 16));
        float v0 = b2f((u16)vu), v1 = b2f((u16)(vu >> 16));
        float s0 = b2f((u16)su), s1 = b2f((u16)(su >> 16));
        float t0 = fmaxf(u0 + k0, e0);
        float x10 = __expf(e0 - t0), x20 = __expf(u0 + k0 - t0);
        float wkv0 = __fdividef(fmaf(x10, a0, x20 * v0), fmaf(x10, b0, x20));
        float t1 = fmaxf(u1 + k1, e1);
        float x11 = __expf(e1 - t1), x21 = __expf(u1 + k1 - t1);
        float wkv1 = __fdividef(fmaf(x11, a1, x21 * v1), fmaf(x11, b1, x21));
        *(u32*)(Pp + base + (i << 10)) = (u32)f2b(wkv0 * s0) | ((u32)f2b(wkv1 * s1) << 16);
        float en0 = fmaxf(e0 - w0, k0);
        float f10 = __expf(e0 - w0 - en0), f20 = __expf(k0 - en0);
        a0 = fmaf(f10, a0, f20 * v0); b0 = fmaf(f10, b0, f20); e0 = en0;
        float en1 = fmaxf(e1 - w1, k1);
        float f11 = __expf(e1 - w1 - en1), f21 = __expf(k1 - en1);
        a1 = fmaf(f11, a1, f21 * v1); b1 = fmaf(f11, b1, f21); e1 = en1;
    }
}

extern "C" void kernel_launch(void* const* d_in, const int* in_sizes, int n_in,
                              void* d_out, int out_size, void* d_ws, size_t ws_size,
                              hipStream_t stream) {
    const float* x      = (const float*)d_in[0];
    const float* Wk     = (const float*)d_in[2];
    const float* Wv     = (const float*)d_in[3];
    const float* Wr     = (const float*)d_in[4];
    const float* Wo     = (const float*)d_in[5];
    const float* tmk    = (const float*)d_in[6];
    const float* tmv    = (const float*)d_in[7];
    const float* tmr    = (const float*)d_in[8];
    const float* tdec   = (const float*)d_in[9];
    const float* tfirst = (const float*)d_in[10];
    const float* lastx  = (const float*)d_in[11];
    const float* state  = (const float*)d_in[12];
    float* out = (float*)d_out;

    const size_t MB = 1024ull * 1024ull;
    char* ws = (char*)d_ws;
    u16* Kb   = (u16*)(ws);                  // 32 MB
    u16* Vb   = (u16*)(ws + 32 * MB);        // 32 MB
    u16* SRb  = (u16*)(ws + 64 * MB);        // 32 MB
    u16* xb   = (u16*)(ws + 96 * MB);        // 32 MB; reused as P after gemm_kvr
    u16* Wall = (u16*)(ws + 128 * MB);       // 8 MB (Wk',Wv',Wr',Wo)
    float* bias = (float*)(ws + 136 * MB);   // 96 KB
    float* Ca = (float*)(ws + 137 * MB);     // 1 MB each
    float* Cb = Ca + 262144;
    float* Ce = Cb + 262144;
    float* Sa = Ce + 262144;
    float* Sb = Sa + 262144;
    float* Se = Sb + 262144;
    u16* Pb = xb;

    dim3 blk(256);
    convx<<<16384, blk, 0, stream>>>(x, xb);
    prepw<<<4096, blk, 0, stream>>>(Wk, Wv, Wr, Wo, tmk, tmv, tmr, Wall);
    bias3<<<768, blk, 0, stream>>>(Wk, Wv, Wr, tmk, tmv, tmr, lastx, bias);
    gemm_kvr<<<dim3(128, 24), blk, 0, stream>>>(xb, Wall, bias, Kb, Vb, SRb);
    wkv_pass1<<<512, blk, 0, stream>>>(Kb, Vb, tdec, Ca, Cb, Ce);
    wkv_pass2<<<32, blk, 0, stream>>>(state, tdec, Ca, Cb, Ce, Sa, Sb, Se);
    wkv_pass3<<<512, blk, 0, stream>>>(Kb, Vb, SRb, Sa, Sb, Se, tfirst, tdec, Pb);
    gemm_out<<<dim3(128, 8), blk, 0, stream>>>(Pb, Wall + 3145728, out);
}